// Round 4
// baseline (8116.314 us; speedup 1.0000x reference)
//
#include <hip/hip_runtime.h>
#include <cstdint>
#include <cstddef>
#include <cstdio>

typedef __bf16 bf16;
typedef __bf16 bf16x8 __attribute__((ext_vector_type(8)));
typedef float f32x4 __attribute__((ext_vector_type(4)));

#define DEVFN __device__ __forceinline__

DEVFN float geluf(float x) { return 0.5f * x * (1.0f + erff(x * 0.70710678118654752f)); }
DEVFN float sigmoidf(float x) { return 1.0f / (1.0f + expf(-x)); }

// ---------------------------------------------------------------------------
// Generic MFMA GEMM: C(M,N) = act(A(M,K) @ W(N,K)^T + bias) [+ residual]
// A, W, C, Rsd are bf16 (workspace); bias is fp32 (may point at input data).
// BM = 64*WGM, BN = 64*WGN, each wave computes a 64x64 tile via 4x4 MFMAs.
// ACT: 0=none, 1=tanh, 2=gelu(exact). Staging: global->reg->ds_write_b128.
// ---------------------------------------------------------------------------
template <int WGM, int WGN, int ACT, bool RES>
__launch_bounds__(WGM * WGN * 64)
__global__ void gemm_bt(const bf16* __restrict__ A, const bf16* __restrict__ W,
                        const float* __restrict__ bias, const bf16* __restrict__ Rsd,
                        bf16* __restrict__ C, int M, int N, int K) {
  constexpr int BM = WGM * 64, BN = WGN * 64, T = WGM * WGN * 64;
  constexpr int NA = BM * 4 / T, NB = BN * 4 / T;
  __shared__ __align__(16) char ldsA[BM * 64];
  __shared__ __align__(16) char ldsB[BN * 64];
  const int tid = threadIdx.x;
  const int lane = tid & 63, wave = tid >> 6;
  const int wm = wave % WGM, wn = wave / WGM;
  const int l16 = lane & 15, quad = lane >> 4;
  const int bm0 = blockIdx.x * BM, bn0 = blockIdx.y * BN;

  f32x4 acc[4][4] = {};
  for (int k0 = 0; k0 < K; k0 += 32) {
    bf16x8 ta[NA], tb[NB];
#pragma unroll
    for (int i = 0; i < NA; ++i) {
      int lin = i * T + tid;
      int row = lin >> 2, seg = lin & 3;
      ta[i] = *(const bf16x8*)(A + (size_t)(bm0 + row) * K + k0 + seg * 8);
    }
#pragma unroll
    for (int i = 0; i < NB; ++i) {
      int lin = i * T + tid;
      int row = lin >> 2, seg = lin & 3;
      tb[i] = *(const bf16x8*)(W + (size_t)(bn0 + row) * K + k0 + seg * 8);
    }
#pragma unroll
    for (int i = 0; i < NA; ++i) *(bf16x8*)(ldsA + (i * T + tid) * 16) = ta[i];
#pragma unroll
    for (int i = 0; i < NB; ++i) *(bf16x8*)(ldsB + (i * T + tid) * 16) = tb[i];
    __syncthreads();
    bf16x8 af[4], bfrag[4];
#pragma unroll
    for (int mi = 0; mi < 4; ++mi)
      af[mi] = *(const bf16x8*)(ldsA + (wm * 64 + mi * 16 + l16) * 64 + quad * 16);
#pragma unroll
    for (int ni = 0; ni < 4; ++ni)
      bfrag[ni] = *(const bf16x8*)(ldsB + (wn * 64 + ni * 16 + l16) * 64 + quad * 16);
#pragma unroll
    for (int mi = 0; mi < 4; ++mi)
#pragma unroll
      for (int ni = 0; ni < 4; ++ni)
        acc[mi][ni] = __builtin_amdgcn_mfma_f32_16x16x32_bf16(af[mi], bfrag[ni], acc[mi][ni], 0, 0, 0);
    __syncthreads();
  }
#pragma unroll
  for (int mi = 0; mi < 4; ++mi) {
#pragma unroll
    for (int ni = 0; ni < 4; ++ni) {
      int col = bn0 + wn * 64 + ni * 16 + l16;
      float bv = bias[col];
#pragma unroll
      for (int r = 0; r < 4; ++r) {
        int row = bm0 + wm * 64 + mi * 16 + quad * 4 + r;
        float x = acc[mi][ni][r] + bv;
        if (ACT == 1) x = tanhf(x);
        if (ACT == 2) x = geluf(x);
        size_t idx = (size_t)row * N + col;
        if (RES) x += (float)Rsd[idx];
        C[idx] = (bf16)x;
      }
    }
  }
}

// ---------------------------------------------------------------------------
// One LSTM time step. Gate weights row-reordered: unit j's gates at rows
// 4j..4j+3. g = xg_t[b] + h_in @ whh'^T ; pointwise -> c (fp32, in-place),
// h (bf16, ping-pong), sequence output slot. xg_t/out_t are pre-offset for
// this t; sb_* are the per-batch-row element strides (layout-agnostic).
// Block: 64 batch rows x 128 gate cols (=32 units), 128 thr. Grid (4,16,nz).
// ---------------------------------------------------------------------------
struct StepDir {
  const bf16* whh;     // (2048,512) reordered
  const bf16* xg_t;    // + b*sb_xg + gatecol
  const bf16* hin;     // (256,512)
  bf16* hout;          // (256,512)
  float* c;            // (256,512) fp32, in-place
  bf16* out_t;         // + b*sb_out + j
  long long sb_xg;
  long long sb_out;
};

__launch_bounds__(128)
__global__ void lstm_step(StepDir da, StepDir db) {
  const StepDir d = (blockIdx.z == 0) ? da : db;
  constexpr int BM = 64, BN = 128, T = 128, BNP = BN + 4;
  __shared__ __align__(16) char ldsA[BM * 64];
  __shared__ __align__(16) char ldsB[BN * 64];
  __shared__ float ldsG[BM * BNP];
  const int tid = threadIdx.x;
  const int lane = tid & 63;
  const int wn = tid >> 6;
  const int l16 = lane & 15, quad = lane >> 4;
  const int bm0 = blockIdx.x * BM;
  const int bn0 = blockIdx.y * BN;

  f32x4 acc[4][4] = {};
  for (int k0 = 0; k0 < 512; k0 += 32) {
    bf16x8 ta[2], tb[4];
#pragma unroll
    for (int i = 0; i < 2; ++i) {
      int lin = i * T + tid;
      int row = lin >> 2, seg = lin & 3;
      ta[i] = *(const bf16x8*)(d.hin + (size_t)(bm0 + row) * 512 + k0 + seg * 8);
    }
#pragma unroll
    for (int i = 0; i < 4; ++i) {
      int lin = i * T + tid;
      int row = lin >> 2, seg = lin & 3;
      tb[i] = *(const bf16x8*)(d.whh + (size_t)(bn0 + row) * 512 + k0 + seg * 8);
    }
#pragma unroll
    for (int i = 0; i < 2; ++i) *(bf16x8*)(ldsA + (i * T + tid) * 16) = ta[i];
#pragma unroll
    for (int i = 0; i < 4; ++i) *(bf16x8*)(ldsB + (i * T + tid) * 16) = tb[i];
    __syncthreads();
    bf16x8 af[4], bfrag[4];
#pragma unroll
    for (int mi = 0; mi < 4; ++mi)
      af[mi] = *(const bf16x8*)(ldsA + (mi * 16 + l16) * 64 + quad * 16);
#pragma unroll
    for (int ni = 0; ni < 4; ++ni)
      bfrag[ni] = *(const bf16x8*)(ldsB + (wn * 64 + ni * 16 + l16) * 64 + quad * 16);
#pragma unroll
    for (int mi = 0; mi < 4; ++mi)
#pragma unroll
      for (int ni = 0; ni < 4; ++ni)
        acc[mi][ni] = __builtin_amdgcn_mfma_f32_16x16x32_bf16(af[mi], bfrag[ni], acc[mi][ni], 0, 0, 0);
    __syncthreads();
  }
  // gates -> LDS (fp32), adding the precomputed input transform
#pragma unroll
  for (int mi = 0; mi < 4; ++mi) {
#pragma unroll
    for (int ni = 0; ni < 4; ++ni) {
      int col_l = wn * 64 + ni * 16 + l16;
      int col_g = bn0 + col_l;
#pragma unroll
      for (int r = 0; r < 4; ++r) {
        int row_l = mi * 16 + quad * 4 + r;
        int b = bm0 + row_l;
        float x = acc[mi][ni][r] + (float)d.xg_t[(size_t)b * d.sb_xg + col_g];
        ldsG[row_l * BNP + col_l] = x;
      }
    }
  }
  __syncthreads();
  // pointwise LSTM update: 64 batch x 32 units per block
  for (int idx = tid; idx < BM * (BN / 4); idx += T) {
    int bl = idx >> 5;
    int jl = idx & 31;
    const float* g4 = &ldsG[bl * BNP + 4 * jl];
    float gi = g4[0], gf = g4[1], gg = g4[2], go = g4[3];
    int b = bm0 + bl;
    int j = (bn0 >> 2) + jl;
    float cprev = d.c[b * 512 + j];
    float cn = sigmoidf(gf) * cprev + sigmoidf(gi) * tanhf(gg);
    float hn = sigmoidf(go) * tanhf(cn);
    d.c[b * 512 + j] = cn;
    bf16 hb = (bf16)hn;
    d.hout[b * 512 + j] = hb;
    d.out_t[(size_t)b * d.sb_out + j] = hb;
  }
}

// ---------------------------------------------------------------------------
// fc_in MLP: 4 -> 32 -> 64 -> 128, exact GELU. One row per thread.
// x and weights are fp32 (input tensors); y is bf16 (workspace).
// trans=1: input row (b*128+s) written to output row (s*256+b) (time-major).
// ---------------------------------------------------------------------------
__launch_bounds__(256)
__global__ void fc_in_mlp(const float* __restrict__ x, bf16* __restrict__ y, int rows, int trans,
                          const float* __restrict__ w1, const float* __restrict__ b1,
                          const float* __restrict__ w2, const float* __restrict__ b2,
                          const float* __restrict__ w3, const float* __restrict__ b3) {
  __shared__ float sm[10592];  // W1[128] B1[32] W2[2048] B2[64] W3[8192] B3[128]
  const int tid = threadIdx.x;
  for (int i = tid; i < 10592; i += 256) {
    float v;
    if (i < 128) v = w1[i];
    else if (i < 160) v = b1[i - 128];
    else if (i < 2208) v = w2[i - 160];
    else if (i < 2272) v = b2[i - 2208];
    else if (i < 10464) v = w3[i - 2272];
    else v = b3[i - 10464];
    sm[i] = v;
  }
  __syncthreads();
  int row = blockIdx.x * 256 + tid;
  if (row >= rows) return;
  int orow = trans ? ((row & 127) * 256 + (row >> 7)) : row;
  float xin[4];
#pragma unroll
  for (int k = 0; k < 4; ++k) xin[k] = x[(size_t)row * 4 + k];
  float h1[32];
#pragma unroll
  for (int j = 0; j < 32; ++j) {
    float a = sm[128 + j];
#pragma unroll
    for (int k = 0; k < 4; ++k) a += sm[j * 4 + k] * xin[k];
    h1[j] = geluf(a);
  }
  float h2[64];
#pragma unroll
  for (int j = 0; j < 64; ++j) {
    float a = sm[2208 + j];
#pragma unroll
    for (int k = 0; k < 32; ++k) a += sm[160 + j * 32 + k] * h1[k];
    h2[j] = geluf(a);
  }
  for (int c = 0; c < 8; ++c) {  // c dynamic to bound code size
    float accv[16];
#pragma unroll
    for (int j = 0; j < 16; ++j) accv[j] = sm[10464 + c * 16 + j];
#pragma unroll
    for (int j = 0; j < 16; ++j) {
#pragma unroll
      for (int k = 0; k < 64; ++k) accv[j] += sm[2272 + (c * 16 + j) * 64 + k] * h2[k];
    }
#pragma unroll
    for (int j = 0; j < 16; ++j) y[(size_t)orow * 128 + c * 16 + j] = (bf16)accv[j];
  }
}

// ---------------------------------------------------------------------------
// fc_out tail: (already-GELU'd 64, bf16) -> 32 (gelu) -> 4, out = trg + delta
// trg, weights, out are fp32.
// ---------------------------------------------------------------------------
__launch_bounds__(256)
__global__ void fc_out_tail(const bf16* __restrict__ h1in, const float* __restrict__ trg,
                            float* __restrict__ out, int rows,
                            const float* __restrict__ w2, const float* __restrict__ b2,
                            const float* __restrict__ w3, const float* __restrict__ b3) {
  __shared__ float sm[2212];  // W2[2048] B2[32] W3[128] B3[4]
  const int tid = threadIdx.x;
  for (int i = tid; i < 2212; i += 256) {
    float v;
    if (i < 2048) v = w2[i];
    else if (i < 2080) v = b2[i - 2048];
    else if (i < 2208) v = w3[i - 2080];
    else v = b3[i - 2208];
    sm[i] = v;
  }
  __syncthreads();
  int row = blockIdx.x * 256 + tid;
  if (row >= rows) return;
  float h1[64];
#pragma unroll
  for (int k = 0; k < 64; ++k) h1[k] = (float)h1in[(size_t)row * 64 + k];
  float h2[32];
#pragma unroll
  for (int j = 0; j < 32; ++j) {
    float a = sm[2048 + j];
#pragma unroll
    for (int k = 0; k < 64; ++k) a += sm[j * 64 + k] * h1[k];
    h2[j] = geluf(a);
  }
#pragma unroll
  for (int dd = 0; dd < 4; ++dd) {
    float a = sm[2208 + dd];
#pragma unroll
    for (int k = 0; k < 32; ++k) a += sm[2080 + dd * 32 + k] * h2[k];
    out[(size_t)row * 4 + dd] = trg[(size_t)row * 4 + dd] + a;
  }
}

// ---------------------------------------------------------------------------
// MHA core: one block per (batch, head). 64 q rows (b-major), 128 keys
// (time-major: row s*256+b), dh=32. All operands bf16 workspace.
// ---------------------------------------------------------------------------
__launch_bounds__(128)
__global__ void attention_kernel(const bf16* __restrict__ Q, const bf16* __restrict__ K,
                                 const bf16* __restrict__ V, bf16* __restrict__ O) {
  __shared__ bf16 qs[64 * 32];
  __shared__ float ks[128 * 33];
  __shared__ bf16 vs[128 * 32];
  __shared__ float sc[64 * 132];
  const int b = blockIdx.x, h = blockIdx.y, tid = threadIdx.x;
  for (int i = tid; i < 64 * 32; i += 128) {
    int t = i >> 5, dd = i & 31;
    qs[i] = Q[((size_t)b * 64 + t) * 128 + h * 32 + dd];
  }
  for (int i = tid; i < 128 * 32; i += 128) {
    int s = i >> 5, dd = i & 31;
    size_t ridx = ((size_t)s * 256 + b) * 128 + h * 32 + dd;
    ks[s * 33 + dd] = (float)K[ridx];
    vs[i] = V[ridx];
  }
  __syncthreads();
  const float scale = 0.17677669529663687f;  // 1/sqrt(32)
  for (int i = tid; i < 64 * 128; i += 128) {
    int t = i >> 7, s = i & 127;
    float a = 0.f;
#pragma unroll
    for (int dd = 0; dd < 32; ++dd) a += (float)qs[t * 32 + dd] * ks[s * 33 + dd];
    sc[t * 132 + s] = a * scale;
  }
  __syncthreads();
  if (tid < 64) {
    float m = -1e30f;
    for (int s = 0; s < 128; ++s) m = fmaxf(m, sc[tid * 132 + s]);
    float sum = 0.f;
    for (int s = 0; s < 128; ++s) { float e = expf(sc[tid * 132 + s] - m); sc[tid * 132 + s] = e; sum += e; }
    float r = 1.0f / sum;
    for (int s = 0; s < 128; ++s) sc[tid * 132 + s] *= r;
  }
  __syncthreads();
  for (int i = tid; i < 64 * 32; i += 128) {
    int t = i >> 5, dd = i & 31;
    float a = 0.f;
    for (int s = 0; s < 128; ++s) a += sc[t * 132 + s] * (float)vs[s * 32 + dd];
    O[((size_t)b * 64 + t) * 128 + h * 32 + dd] = (bf16)a;
  }
}

// ---------------------------------------------------------------------------
// Prep kernels (all convert fp32 input data -> bf16/fp32 workspace)
// ---------------------------------------------------------------------------
// row r = gate*512 + j  ->  new row 4*j + gate  (i,f,g,o interleaved per unit)
__global__ void reorder_gate_rows(const float* __restrict__ in, bf16* __restrict__ out, int K) {
  int i = blockIdx.x * 256 + threadIdx.x;
  if (i >= 2048 * K) return;
  int r = i / K, k = i - r * K;
  int nr = 4 * (r & 511) + (r >> 9);
  out[(size_t)nr * K + k] = (bf16)in[i];
}

__global__ void combine_bias(const float* __restrict__ a, const float* __restrict__ b,
                             float* __restrict__ out) {
  int i = blockIdx.x * 256 + threadIdx.x;
  if (i >= 2048) return;
  out[4 * (i & 511) + (i >> 9)] = a[i] + b[i];
}

__global__ void f2b(const float* __restrict__ in, bf16* __restrict__ out, int n) {
  int i = blockIdx.x * 256 + threadIdx.x;
  if (i < n) out[i] = (bf16)in[i];
}

__global__ void zero_u32(uint32_t* __restrict__ p, int n) {
  int i = blockIdx.x * 256 + threadIdx.x;
  if (i < n) p[i] = 0u;
}

__global__ void dec_state_init(const bf16* __restrict__ hf, const bf16* __restrict__ hb,
                               const float* __restrict__ cf, const float* __restrict__ cb,
                               bf16* __restrict__ hout, float* __restrict__ cout) {
  int i = blockIdx.x * 256 + threadIdx.x;
  if (i >= 256 * 512) return;
  hout[i] = (bf16)((float)hf[i] + (float)hb[i]);
  cout[i] = cf[i] + cb[i];
}

// ---------------------------------------------------------------------------
// Host
// ---------------------------------------------------------------------------
extern "C" void kernel_launch(void* const* d_in, const int* in_sizes, int n_in,
                              void* d_out, int out_size, void* d_ws, size_t ws_size,
                              hipStream_t stream) {
  (void)in_sizes; (void)n_in; (void)out_size;
  const float* src = (const float*)d_in[0];
  const float* trg = (const float*)d_in[1];
  const float* fi_w1 = (const float*)d_in[2];
  const float* fi_b1 = (const float*)d_in[3];
  const float* fi_w2 = (const float*)d_in[4];
  const float* fi_b2 = (const float*)d_in[5];
  const float* fi_w3 = (const float*)d_in[6];
  const float* fi_b3 = (const float*)d_in[7];
  // LSTM param order: e0f, e0b, e1f, e1b, d0, d1
  const float* wih_in[6] = {(const float*)d_in[8],  (const float*)d_in[12], (const float*)d_in[16],
                            (const float*)d_in[20], (const float*)d_in[30], (const float*)d_in[34]};
  const float* whh_in[6] = {(const float*)d_in[9],  (const float*)d_in[13], (const float*)d_in[17],
                            (const float*)d_in[21], (const float*)d_in[31], (const float*)d_in[35]};
  const float* bih_in[6] = {(const float*)d_in[10], (const float*)d_in[14], (const float*)d_in[18],
                            (const float*)d_in[22], (const float*)d_in[32], (const float*)d_in[36]};
  const float* bhh_in[6] = {(const float*)d_in[11], (const float*)d_in[15], (const float*)d_in[19],
                            (const float*)d_in[23], (const float*)d_in[33], (const float*)d_in[37]};
  const int kin[6] = {128, 128, 1024, 1024, 128, 512};
  const float* attnfc_w = (const float*)d_in[24];
  const float* attnfc_b = (const float*)d_in[25];
  const float* inproj_w = (const float*)d_in[26];
  const float* inproj_b = (const float*)d_in[27];
  const float* outproj_w = (const float*)d_in[28];
  const float* outproj_b = (const float*)d_in[29];
  const float* fo_w1 = (const float*)d_in[38];
  const float* fo_b1 = (const float*)d_in[39];
  const float* fo_w2 = (const float*)d_in[40];
  const float* fo_b2 = (const float*)d_in[41];
  const float* fo_w3 = (const float*)d_in[42];
  const float* fo_b3 = (const float*)d_in[43];
  float* out = (float*)d_out;

  // ---- workspace carve (phase-based region reuse; in-order stream) ----
  char* base = (char*)d_ws;
  size_t o = 0;
  auto take = [&](size_t bytes) -> char* {
    char* p = base + o;
    o = (o + bytes + 255) & ~(size_t)255;
    return p;
  };
  bf16* wr_whh[6]; for (int i = 0; i < 6; ++i) wr_whh[i] = (bf16*)take((size_t)2048 * 512 * 2);
  bf16* wr_wih[6]; for (int i = 0; i < 6; ++i) wr_wih[i] = (bf16*)take((size_t)2048 * kin[i] * 2);
  float* bias_l[6]; for (int i = 0; i < 6; ++i) bias_l[i] = (float*)take(2048 * 4);
  bf16* attnfc_wb = (bf16*)take((size_t)128 * 1024 * 2);
  bf16* inproj_wb = (bf16*)take((size_t)384 * 128 * 2);
  bf16* outproj_wb = (bf16*)take((size_t)128 * 128 * 2);
  bf16* fo_w1b = (bf16*)take((size_t)64 * 512 * 2);
  bf16* h_a0 = (bf16*)take((size_t)6 * 256 * 512 * 2);   // h_a[0..5] contiguous
  bf16* h_b0 = (bf16*)take((size_t)6 * 256 * 512 * 2);   // h_b[0..5] contiguous
  float* c_0 = (float*)take((size_t)6 * 256 * 512 * 4);  // c[0..5] contiguous
  bf16* h_a[6]; bf16* h_b[6]; float* c_s[6];
  for (int i = 0; i < 6; ++i) {
    h_a[i] = h_a0 + (size_t)i * 256 * 512;
    h_b[i] = h_b0 + (size_t)i * 256 * 512;
    c_s[i] = c_0 + (size_t)i * 256 * 512;
  }
  // Region 1 (64 MiB): x1 (time-major, whole encoder) ; after encoder done:
  //   proj_enc/inp/qb/kb/vb/attnb/dec_in/fc1out
  char* R1 = take((size_t)64 << 20);
  // Region 2 (64 MiB): embed_src (layer-0 phase) -> enc_out (layer-1 phase)
  //   -> xg_dec (decoder phase)
  char* R2 = take((size_t)64 << 20);
  // Region 3 (32 MiB): xgA+xgB chunk buffers -> d0_seq+d1_seq
  char* R3 = take((size_t)32 << 20);
  size_t required = o;
  if (required > ws_size) {
    fprintf(stderr, "[kernel_launch] ws_size=%zu < required=%zu — aborting launch\n",
            ws_size, required);
    return;
  }

  bf16* x1       = (bf16*)R1;                                   // (128,256,1024) time-major
  bf16* proj_enc = (bf16*)R1;                                   // (128,256,128) time-major
  bf16* inp      = (bf16*)(R1 + ((size_t)8 << 20));             // (256,64,128) b-major
  bf16* qb       = (bf16*)(R1 + ((size_t)12 << 20));
  bf16* kb       = (bf16*)(R1 + ((size_t)16 << 20));
  bf16* vb       = (bf16*)(R1 + ((size_t)24 << 20));
  bf16* attnb    = (bf16*)(R1 + ((size_t)32 << 20));
  bf16* dec_in   = (bf16*)(R1 + ((size_t)36 << 20));
  bf16* fc1out   = (bf16*)(R1 + ((size_t)40 << 20));
  bf16* embed    = (bf16*)R2;                                   // (128,256,128) time-major
  bf16* enc_out  = (bf16*)R2;                                   // (128,256,1024) time-major
  bf16* xg_dec   = (bf16*)R2;                                   // (256,64,2048) b-major
  bf16* xgA      = (bf16*)R3;                                   // 16-step chunk, fwd
  bf16* xgB      = (bf16*)(R3 + ((size_t)16 << 20));            // 16-step chunk, bwd
  bf16* d0_seq   = (bf16*)R3;                                   // (256,64,512) b-major
  bf16* d1_seq   = (bf16*)(R3 + ((size_t)16 << 20));

  // ---- prep: convert+reorder weights, combine biases, zero initial states ----
  for (int i = 0; i < 6; ++i) {
    int K2 = kin[i];
    reorder_gate_rows<<<dim3((2048 * K2 + 255) / 256), 256, 0, stream>>>(wih_in[i], wr_wih[i], K2);
    reorder_gate_rows<<<dim3((2048 * 512 + 255) / 256), 256, 0, stream>>>(whh_in[i], wr_whh[i], 512);
    combine_bias<<<dim3(8), 256, 0, stream>>>(bih_in[i], bhh_in[i], bias_l[i]);
  }
  f2b<<<dim3(512), 256, 0, stream>>>(attnfc_w, attnfc_wb, 128 * 1024);
  f2b<<<dim3(192), 256, 0, stream>>>(inproj_w, inproj_wb, 384 * 128);
  f2b<<<dim3(64), 256, 0, stream>>>(outproj_w, outproj_wb, 128 * 128);
  f2b<<<dim3(128), 256, 0, stream>>>(fo_w1, fo_w1b, 64 * 512);
  zero_u32<<<dim3(1024), 256, 0, stream>>>((uint32_t*)h_a0, 4 * 256 * 512 / 2);  // h_a[0..3]
  zero_u32<<<dim3(2048), 256, 0, stream>>>((uint32_t*)c_0, 4 * 256 * 512);       // c[0..3]

  // ---- fc_in on src (time-major output) ----
  fc_in_mlp<<<dim3(128), 256, 0, stream>>>(src, embed, 32768, 1, fi_w1, fi_b1, fi_w2, fi_b2, fi_w3, fi_b3);

  // ---- encoder: 16-step-chunked xg + recurrence, both layers ----
  const int CH = 16, NC = 128 / CH;
  for (int layer = 0; layer < 2; ++layer) {
    const bf16* lin = layer ? x1 : embed;
    bf16* lout = layer ? enc_out : x1;
    int K2 = layer ? 1024 : 128;
    int wf = layer ? 2 : 0, wb = layer ? 3 : 1;
    for (int c = 0; c < NC; ++c) {
      int t0f = c * CH, t0b = 128 - (c + 1) * CH;
      // input-gate GEMM for this chunk, both directions (rows contiguous in time-major)
      gemm_bt<2, 2, 0, false><<<dim3(CH * 2, 16), 256, 0, stream>>>(lin + (size_t)t0f * 256 * K2, wr_wih[wf], bias_l[wf], nullptr, xgA, CH * 256, 2048, K2);
      gemm_bt<2, 2, 0, false><<<dim3(CH * 2, 16), 256, 0, stream>>>(lin + (size_t)t0b * 256 * K2, wr_wih[wb], bias_l[wb], nullptr, xgB, CH * 256, 2048, K2);
      for (int i = 0; i < CH; ++i) {
        int tt = c * CH + i, tb = 127 - tt;
        bool odd = (tt & 1) != 0;
        StepDir f{wr_whh[wf], xgA + (size_t)i * 256 * 2048,
                  odd ? h_b[wf] : h_a[wf], odd ? h_a[wf] : h_b[wf], c_s[wf],
                  lout + (size_t)tt * 256 * 1024, 2048, 1024};
        StepDir bwd{wr_whh[wb], xgB + (size_t)(CH - 1 - i) * 256 * 2048,
                    odd ? h_b[wb] : h_a[wb], odd ? h_a[wb] : h_b[wb], c_s[wb],
                    lout + (size_t)tb * 256 * 1024 + 512, 2048, 1024};
        lstm_step<<<dim3(4, 16, 2), 128, 0, stream>>>(f, bwd);
      }
    }
  }

  // ---- attnfc (tanh), time-major rows ----
  gemm_bt<2, 2, 1, false><<<dim3(256, 1), 256, 0, stream>>>(enc_out, attnfc_wb, attnfc_b, nullptr, proj_enc, 32768, 128, 1024);

  // ---- fc_in on trg (b-major) ----
  fc_in_mlp<<<dim3(64), 256, 0, stream>>>(trg, inp, 16384, 0, fi_w1, fi_b1, fi_w2, fi_b2, fi_w3, fi_b3);

  // ---- MHA ----
  gemm_bt<2, 2, 0, false><<<dim3(128, 1), 256, 0, stream>>>(inp, inproj_wb, inproj_b, nullptr, qb, 16384, 128, 128);
  gemm_bt<2, 2, 0, false><<<dim3(256, 1), 256, 0, stream>>>(proj_enc, inproj_wb + (size_t)128 * 128, inproj_b + 128, nullptr, kb, 32768, 128, 128);
  gemm_bt<2, 2, 0, false><<<dim3(256, 1), 256, 0, stream>>>(proj_enc, inproj_wb + (size_t)256 * 128, inproj_b + 256, nullptr, vb, 32768, 128, 128);
  attention_kernel<<<dim3(256, 4), 128, 0, stream>>>(qb, kb, vb, attnb);
  gemm_bt<2, 2, 0, true><<<dim3(128, 1), 256, 0, stream>>>(attnb, outproj_wb, outproj_b, inp, dec_in, 16384, 128, 128);

  // ---- decoder initial states: sum fwd+bwd finals (final h lives in h_a) ----
  dec_state_init<<<dim3(512), 256, 0, stream>>>(h_a[0], h_a[1], c_s[0], c_s[1], h_a[4], c_s[4]);
  dec_state_init<<<dim3(512), 256, 0, stream>>>(h_a[2], h_a[3], c_s[2], c_s[3], h_a[5], c_s[5]);

  // ---- decoder layer 0 (b-major; xg full-size in R2, enc_out dead) ----
  gemm_bt<2, 2, 0, false><<<dim3(128, 16), 256, 0, stream>>>(dec_in, wr_wih[4], bias_l[4], nullptr, xg_dec, 16384, 2048, 128);
  for (int t = 0; t < 64; ++t) {
    bool odd = (t & 1) != 0;
    StepDir f{wr_whh[4], xg_dec + (size_t)t * 2048,
              odd ? h_b[4] : h_a[4], odd ? h_a[4] : h_b[4], c_s[4],
              d0_seq + (size_t)t * 512, 64 * 2048, 64 * 512};
    lstm_step<<<dim3(4, 16, 1), 128, 0, stream>>>(f, f);
  }

  // ---- decoder layer 1 ----
  gemm_bt<2, 2, 0, false><<<dim3(128, 16), 256, 0, stream>>>(d0_seq, wr_wih[5], bias_l[5], nullptr, xg_dec, 16384, 2048, 512);
  for (int t = 0; t < 64; ++t) {
    bool odd = (t & 1) != 0;
    StepDir f{wr_whh[5], xg_dec + (size_t)t * 2048,
              odd ? h_b[5] : h_a[5], odd ? h_a[5] : h_b[5], c_s[5],
              d1_seq + (size_t)t * 512, 64 * 2048, 64 * 512};
    lstm_step<<<dim3(4, 16, 1), 128, 0, stream>>>(f, f);
  }

  // ---- fc_out ----
  gemm_bt<2, 1, 2, false><<<dim3(128, 1), 128, 0, stream>>>(d1_seq, fo_w1b, fo_b1, nullptr, fc1out, 16384, 64, 512);
  fc_out_tail<<<dim3(64), 256, 0, stream>>>(fc1out, trg, out, 16384, fo_w2, fo_b2, fo_w3, fo_b3);
}